// Round 7
// baseline (696.062 us; speedup 1.0000x reference)
//
#include <hip/hip_runtime.h>
#include <hip/hip_bf16.h>
#include <math.h>

#define B_ 32
#define E_ 16384
#define N_ 1000
#define D_ 128
#define NN_ (N_ * N_)
#define T_ 4   // 256-edge sub-tiles per block; grid = B_*E_/(256*T_) = 512

typedef __attribute__((ext_vector_type(8))) short bf16x8;
typedef __attribute__((ext_vector_type(4))) float f32x4;

// fp32 -> bf16 RNE (scalar; finite inputs)
__device__ __forceinline__ unsigned short f2bf(float f) {
    unsigned u = __float_as_uint(f);
    u += 0x7FFFu + ((u >> 16) & 1u);
    return (unsigned short)(u >> 16);
}

// packed pair fp32 -> bf16x2 (v_cvt_pk_bf16_f32)
__device__ __forceinline__ unsigned pk2(float lo, float hi) {
    __hip_bfloat162 h = __float22bfloat162_rn(make_float2(lo, hi));
    return *(unsigned*)&h;
}

__device__ __forceinline__ f32x4 mfma16(bf16x8 a, bf16x8 b, f32x4 c) {
    return __builtin_amdgcn_mfma_f32_16x16x32_bf16(a, b, c, 0, 0, 0);
}

__device__ __forceinline__ float silu_(float z) {
    return z * __builtin_amdgcn_rcpf(1.0f + __expf(-z));
}

// decode 17-bit quantized cell payload (call only when bit31 set; q >= 1)
__device__ __forceinline__ float dec17(unsigned x) {
    return (float)((x & 0x1FFFFu) - 1u) * (10.0f / 131070.0f);
}

// async global->LDS, 16B per lane (dest = wave-uniform base + lane*16)
__device__ __forceinline__ void gload_lds16(const void* g, void* l) {
    __builtin_amdgcn_global_load_lds(
        (const __attribute__((address_space(1))) unsigned*)g,
        (__attribute__((address_space(3))) unsigned*)l, 16, 0, 0);
}

// Pre-swizzle W1,W2 (128x128 fp32) -> bf16 at byte row*256 + ((2*pos)^((row&7)<<4)).
// W1: pos = src column (natural).  W2: COLUMN-PERMUTED so that GEMM1's C-fragment
// feeds GEMM2 directly with NO transpose: k-slot (pos = q*32 + g*8 + nn*4 + r)
// holds logical f1 = (q*2+nn)*16 + g*4 + r — matching where GEMM1's output
// physically lands (lane g holds acc1[nn][r] for that f1).
__global__ void prep_weights(const float* __restrict__ W1,
                             const float* __restrict__ W2,
                             unsigned short* __restrict__ wsz) {
    int t = blockIdx.x * 256 + threadIdx.x;   // 0..32767
    int w = t >> 14, e = t & 16383;
    int row = e >> 7, pos = e & 127;
    int src_col = pos;
    if (w) {
        int q = pos >> 5, gg = (pos >> 3) & 3, nn = (pos >> 2) & 1, r = pos & 3;
        src_col = (q * 2 + nn) * 16 + gg * 4 + r;
    }
    float v = (w ? W2 : W1)[row * 128 + src_col];
    char* dst = (char*)wsz + (size_t)w * 32768 + row * 256 + ((pos * 2) ^ ((row & 7) << 4));
    *(unsigned short*)dst = f2bf(v);
}

__global__ __launch_bounds__(512, 4) void mlp_scatter_kernel(
    const float* __restrict__ X, const int* __restrict__ EI,
    const unsigned short* __restrict__ wsz,
    const float* __restrict__ b1, const float* __restrict__ b2,
    const float* __restrict__ Wo, const float* __restrict__ bo,
    unsigned* __restrict__ out)
{
    __shared__ __align__(16) char Wb[65536];   // W1 | W2 bf16, swizzled
    __shared__ __align__(16) float BiasL[384]; // b1 | b2 | Wo (fp32)

    const int tid = threadIdx.x;
    const int lane = tid & 63;
    const int wv = tid >> 6;          // wave 0..7, owns 32 edges per sub-tile
    const int l15 = lane & 15;
    const int g = (lane >> 4) & 3;

    const int bb = blockIdx.x >> 4;                 // batch (16 blocks per batch)
    const int e0 = (blockIdx.x & 15) * (256 * T_);  // edge base within batch

    if (tid < 96) {
        const float* src = tid < 32 ? b1 : (tid < 64 ? b2 : Wo);
        ((f32x4*)BiasL)[tid] = ((const f32x4*)src)[tid & 31];
    }
    const float bo0 = bo[0];

    // stage both weight matrices: 64KB linear, zero VALU
    #pragma unroll
    for (int it = 0; it < 8; ++it) {
        int off = it * 8192 + tid * 16;
        gload_lds16((const char*)wsz + off, Wb + off);
    }
    __syncthreads();

    for (int st = 0; st < T_; ++st) {
        const int eb0 = e0 + st * 256 + wv * 32;

        int eisv[2], eidv[2];
        #pragma unroll
        for (int m = 0; m < 2; ++m) {
            int e = eb0 + m * 16 + l15;
            eisv[m] = EI[(size_t)bb * 2 * E_ + e];
            eidv[m] = EI[(size_t)bb * 2 * E_ + E_ + e];
        }

        // load X (plain vectorized loads; 16 waves/CU hide the latency via TLP)
        bf16x8 a[2][4];
        #pragma unroll
        for (int m = 0; m < 2; ++m) {
            const float* p0 = X + ((size_t)bb * E_ + eb0 + m * 16 + l15) * D_ + g * 8;
            #pragma unroll
            for (int ks = 0; ks < 4; ++ks) {
                float4 u0 = *(const float4*)(p0 + ks * 32);
                float4 u1 = *(const float4*)(p0 + ks * 32 + 4);
                bf16x8 t; unsigned* tu = (unsigned*)&t;
                tu[0] = pk2(u0.x, u0.y); tu[1] = pk2(u0.z, u0.w);
                tu[2] = pk2(u1.x, u1.y); tu[3] = pk2(u1.z, u1.w);
                a[m][ks] = t;
            }
        }

        f32x4 acc2[2][8];
        #pragma unroll
        for (int m = 0; m < 2; ++m)
            #pragma unroll
            for (int n = 0; n < 8; ++n)
                acc2[m][n] = (f32x4){0.f, 0.f, 0.f, 0.f};

        // quarter-feature pipeline: GEMM1 q -> (bias+silu+pack in REGISTERS) -> GEMM2 q
        #pragma unroll
        for (int q = 0; q < 4; ++q) {
            f32x4 acc1[2][2];
            #pragma unroll
            for (int m = 0; m < 2; ++m)
                #pragma unroll
                for (int nn = 0; nn < 2; ++nn)
                    acc1[m][nn] = (f32x4){0.f, 0.f, 0.f, 0.f};

            #pragma unroll
            for (int ks = 0; ks < 4; ++ks)
                #pragma unroll
                for (int nn = 0; nn < 2; ++nn) {
                    int row = l15 + (q * 2 + nn) * 16;
                    bf16x8 aw = *(const bf16x8*)(Wb + row * 256 +
                                  ((ks * 64 + g * 16) ^ ((row & 7) << 4)));
                    acc1[0][nn] = mfma16(aw, a[0][ks], acc1[0][nn]);
                    acc1[1][nn] = mfma16(aw, a[1][ks], acc1[1][nn]);
                }

            // h fragment built in-register: k-slot (g, j=nn*4+r) = this lane's
            // acc1[m][nn][r] (W2 columns were pre-permuted to match)
            bf16x8 a2[2];
            #pragma unroll
            for (int m = 0; m < 2; ++m) {
                f32x4 b1q0 = ((f32x4*)BiasL)[(q * 2 + 0) * 4 + g];
                f32x4 b1q1 = ((f32x4*)BiasL)[(q * 2 + 1) * 4 + g];
                unsigned* au = (unsigned*)&a2[m];
                au[0] = pk2(silu_(acc1[m][0][0] + b1q0[0]), silu_(acc1[m][0][1] + b1q0[1]));
                au[1] = pk2(silu_(acc1[m][0][2] + b1q0[2]), silu_(acc1[m][0][3] + b1q0[3]));
                au[2] = pk2(silu_(acc1[m][1][0] + b1q1[0]), silu_(acc1[m][1][1] + b1q1[1]));
                au[3] = pk2(silu_(acc1[m][1][2] + b1q1[2]), silu_(acc1[m][1][3] + b1q1[3]));
            }

            #pragma unroll
            for (int n = 0; n < 8; ++n) {
                int row = l15 + n * 16;
                bf16x8 w2 = *(const bf16x8*)(Wb + 32768 + row * 256 +
                              ((q * 64 + g * 16) ^ ((row & 7) << 4)));
                acc2[0][n] = mfma16(w2, a2[0], acc2[0][n]);
                acc2[1][n] = mfma16(w2, a2[1], acc2[1][n]);
            }
        }

        // epilogue: lane holds f2 = n*16+g*4+r for edge m*16+l15
        float zed[2] = {0.f, 0.f};
        #pragma unroll
        for (int n = 0; n < 8; ++n) {
            f32x4 b2q = ((f32x4*)BiasL)[32 + n * 4 + g];
            f32x4 woq = ((f32x4*)BiasL)[64 + n * 4 + g];
            #pragma unroll
            for (int m = 0; m < 2; ++m) {
                zed[m] += silu_(acc2[m][n][0] + b2q[0]) * woq[0];
                zed[m] += silu_(acc2[m][n][1] + b2q[1]) * woq[1];
                zed[m] += silu_(acc2[m][n][2] + b2q[2]) * woq[2];
                zed[m] += silu_(acc2[m][n][3] + b2q[3]) * woq[3];
            }
        }
        #pragma unroll
        for (int m = 0; m < 2; ++m) {
            zed[m] += __shfl_xor(zed[m], 16, 64);
            zed[m] += __shfl_xor(zed[m], 32, 64);
        }

        // sigmoid*10, pack bit31 | e<<17 | q17, atomicMax scatter (last-e-wins)
        if (g == 0) {
            #pragma unroll
            for (int m = 0; m < 2; ++m) {
                int e = eb0 + m * 16 + l15;
                float z = zed[m] + bo0;
                float val = 10.0f * __builtin_amdgcn_rcpf(1.0f + __expf(-z));
                unsigned qv = (unsigned)(val * 13107.0f + 0.5f) + 1u;  // 131070/10
                if (qv > 0x1FFFFu) qv = 0x1FFFFu;
                unsigned packed = 0x80000000u | ((unsigned)e << 17) | qv;
                atomicMax(out + ((size_t)bb * NN_ + (size_t)eisv[m] * N_ + eidv[m]),
                          packed);
            }
        }
    }
}

// Fused finalize. Cell states: 0 = empty (= final 0.0f); bit31 set = packed
// quantized edge value; bit31 clear & nonzero = already-final float in (0,10].
// Every writer of a cell writes the same v, so concurrent/stale reads are
// benign: a stale read sees the packed form and recomputes the identical v.
__global__ __launch_bounds__(256) void finalize_fused(
    const int* __restrict__ EI, unsigned* __restrict__ out)
{
    int i = blockIdx.x * 256 + threadIdx.x;   // 0..B*E-1
    int b = i >> 14, e = i & 16383;
    int s = EI[(size_t)b * 2 * E_ + e];
    int d = EI[(size_t)b * 2 * E_ + E_ + e];
    unsigned* ob = out + (size_t)b * NN_;
    unsigned x1 = ob[(size_t)s * N_ + d];
    unsigned x2 = ob[(size_t)d * N_ + s];
    float v;
    if (!(x1 >> 31) && x1)      v = __uint_as_float(x1);   // already final
    else if (!(x2 >> 31) && x2) v = __uint_as_float(x2);   // already final
    else {
        float c1 = (x1 >> 31) ? dec17(x1) : 0.0f;
        float c2 = (x2 >> 31) ? dec17(x2) : 0.0f;
        v = 0.5f * (c1 + c2);
    }
    unsigned uv = __float_as_uint(v);
    ob[(size_t)s * N_ + d] = uv;
    ob[(size_t)d * N_ + s] = uv;
}

extern "C" void kernel_launch(void* const* d_in, const int* in_sizes, int n_in,
                              void* d_out, int out_size, void* d_ws, size_t ws_size,
                              hipStream_t stream) {
    const float* X  = (const float*)d_in[0];
    const int*   EI = (const int*)d_in[1];
    const float* W1 = (const float*)d_in[2];
    const float* b1 = (const float*)d_in[3];
    const float* W2 = (const float*)d_in[4];
    const float* b2 = (const float*)d_in[5];
    const float* Wo = (const float*)d_in[6];
    const float* bo = (const float*)d_in[7];
    unsigned* out = (unsigned*)d_out;
    unsigned short* wsz = (unsigned short*)d_ws;

    prep_weights<<<dim3(128), dim3(256), 0, stream>>>(W1, W2, wsz);
    hipMemsetAsync(d_out, 0, (size_t)B_ * NN_ * sizeof(float), stream);
    mlp_scatter_kernel<<<dim3((B_ * E_) / (256 * T_)), dim3(512), 0, stream>>>(
        X, EI, wsz, b1, b2, Wo, bo, out);
    finalize_fused<<<dim3((B_ * E_) / 256), dim3(256), 0, stream>>>(EI, out);
}

// Round 8
// 694.681 us; speedup vs baseline: 1.0020x; 1.0020x over previous
//
#include <hip/hip_runtime.h>
#include <hip/hip_bf16.h>
#include <math.h>

#define B_ 32
#define E_ 16384
#define N_ 1000
#define D_ 128
#define NN_ (N_ * N_)
#define T_ 8   // 128-edge sub-tiles per block; grid = B_*E_/(128*T_) = 512 = 2/CU

typedef __attribute__((ext_vector_type(8))) short bf16x8;
typedef __attribute__((ext_vector_type(4))) float f32x4;

// fp32 -> bf16 RNE (scalar; finite inputs)
__device__ __forceinline__ unsigned short f2bf(float f) {
    unsigned u = __float_as_uint(f);
    u += 0x7FFFu + ((u >> 16) & 1u);
    return (unsigned short)(u >> 16);
}

// packed pair fp32 -> bf16x2 (v_cvt_pk_bf16_f32)
__device__ __forceinline__ unsigned pk2(float lo, float hi) {
    __hip_bfloat162 h = __float22bfloat162_rn(make_float2(lo, hi));
    return *(unsigned*)&h;
}

__device__ __forceinline__ f32x4 mfma16(bf16x8 a, bf16x8 b, f32x4 c) {
    return __builtin_amdgcn_mfma_f32_16x16x32_bf16(a, b, c, 0, 0, 0);
}

__device__ __forceinline__ float silu_(float z) {
    return z * __builtin_amdgcn_rcpf(1.0f + __expf(-z));
}

// decode 17-bit quantized cell payload (call only when bit31 set; q >= 1)
__device__ __forceinline__ float dec17(unsigned x) {
    return (float)((x & 0x1FFFFu) - 1u) * (10.0f / 131070.0f);
}

// async global->LDS, 16B per lane (dest = wave-uniform base + lane*16)
__device__ __forceinline__ void gload_lds16(const void* g, void* l) {
    __builtin_amdgcn_global_load_lds(
        (const __attribute__((address_space(1))) unsigned*)g,
        (__attribute__((address_space(3))) unsigned*)l, 16, 0, 0);
}

// Pre-swizzle W1,W2 (128x128 fp32) -> bf16 at byte row*256 + ((2*pos)^((row&7)<<4)).
// W1: pos = src column (natural).  W2: COLUMN-PERMUTED so GEMM1's C-fragment
// feeds GEMM2 directly with NO transpose: k-slot pos = q*32 + g*8 + nn*4 + r
// holds logical f1 = (q*2+nn)*16 + g*4 + r (where GEMM1's output lands).
__global__ void prep_weights(const float* __restrict__ W1,
                             const float* __restrict__ W2,
                             unsigned short* __restrict__ wsz) {
    int t = blockIdx.x * 256 + threadIdx.x;   // 0..32767
    int w = t >> 14, e = t & 16383;
    int row = e >> 7, pos = e & 127;
    int src_col = pos;
    if (w) {
        int q = pos >> 5, gg = (pos >> 3) & 3, nn = (pos >> 2) & 1, r = pos & 3;
        src_col = (q * 2 + nn) * 16 + gg * 4 + r;
    }
    float v = (w ? W2 : W1)[row * 128 + src_col];
    char* dst = (char*)wsz + (size_t)w * 32768 + row * 256 + ((pos * 2) ^ ((row & 7) << 4));
    *(unsigned short*)dst = f2bf(v);
}

__global__ __launch_bounds__(512, 4) void mlp_scatter_kernel(
    const float* __restrict__ X, const int* __restrict__ EI,
    const unsigned short* __restrict__ wsz,
    const float* __restrict__ b1, const float* __restrict__ b2,
    const float* __restrict__ Wo, const float* __restrict__ bo,
    unsigned* __restrict__ out)
{
    __shared__ __align__(16) char Wb[65536];   // W1 | W2 bf16, swizzled
    __shared__ __align__(16) float BiasL[384]; // b1 | b2 | Wo (fp32)

    const int tid = threadIdx.x;
    const int lane = tid & 63;
    const int wv = tid >> 6;          // wave 0..7, owns 16 edges per sub-tile
    const int l15 = lane & 15;
    const int g = (lane >> 4) & 3;

    const int bb = blockIdx.x >> 4;                 // batch (16 blocks per batch)
    const int e0 = (blockIdx.x & 15) * (128 * T_);  // 1024 edges per block

    if (tid < 96) {
        const float* src = tid < 32 ? b1 : (tid < 64 ? b2 : Wo);
        ((f32x4*)BiasL)[tid] = ((const f32x4*)src)[tid & 31];
    }
    const float bo0 = bo[0];

    // stage both weight matrices: 64KB linear, zero VALU
    #pragma unroll
    for (int it = 0; it < 8; ++it) {
        int off = it * 8192 + tid * 16;
        gload_lds16((const char*)wsz + off, Wb + off);
    }
    __syncthreads();

    for (int st = 0; st < T_; ++st) {   // NOT unrolled: limits register liveness
        const int eb0 = e0 + st * 128 + wv * 16;

        const int eis = EI[(size_t)bb * 2 * E_ + eb0 + l15];
        const int eid = EI[(size_t)bb * 2 * E_ + E_ + eb0 + l15];

        // load X for this wave's 16 edges; convert incrementally (low liveness)
        bf16x8 a[4];
        {
            const float* p0 = X + ((size_t)bb * E_ + eb0 + l15) * D_ + g * 8;
            #pragma unroll
            for (int ks = 0; ks < 4; ++ks) {
                float4 u0 = *(const float4*)(p0 + ks * 32);
                float4 u1 = *(const float4*)(p0 + ks * 32 + 4);
                bf16x8 t; unsigned* tu = (unsigned*)&t;
                tu[0] = pk2(u0.x, u0.y); tu[1] = pk2(u0.z, u0.w);
                tu[2] = pk2(u1.x, u1.y); tu[3] = pk2(u1.z, u1.w);
                a[ks] = t;
            }
        }

        f32x4 acc2[8];
        #pragma unroll
        for (int n = 0; n < 8; ++n)
            acc2[n] = (f32x4){0.f, 0.f, 0.f, 0.f};

        // quarter-feature pipeline: GEMM1 q -> (bias+silu+pack in REGS) -> GEMM2 q
        #pragma unroll
        for (int q = 0; q < 4; ++q) {
            f32x4 acc1[2];
            acc1[0] = (f32x4){0.f, 0.f, 0.f, 0.f};
            acc1[1] = (f32x4){0.f, 0.f, 0.f, 0.f};

            #pragma unroll
            for (int ks = 0; ks < 4; ++ks)
                #pragma unroll
                for (int nn = 0; nn < 2; ++nn) {
                    int row = l15 + (q * 2 + nn) * 16;
                    bf16x8 aw = *(const bf16x8*)(Wb + row * 256 +
                                  ((ks * 64 + g * 16) ^ ((row & 7) << 4)));
                    acc1[nn] = mfma16(aw, a[ks], acc1[nn]);
                }

            // h fragment in-register: k-slot (g, nn*4+r) = acc1[nn][r]
            // (W2 columns pre-permuted to match)
            bf16x8 a2;
            {
                f32x4 b1q0 = ((f32x4*)BiasL)[(q * 2 + 0) * 4 + g];
                f32x4 b1q1 = ((f32x4*)BiasL)[(q * 2 + 1) * 4 + g];
                unsigned* au = (unsigned*)&a2;
                au[0] = pk2(silu_(acc1[0][0] + b1q0[0]), silu_(acc1[0][1] + b1q0[1]));
                au[1] = pk2(silu_(acc1[0][2] + b1q0[2]), silu_(acc1[0][3] + b1q0[3]));
                au[2] = pk2(silu_(acc1[1][0] + b1q1[0]), silu_(acc1[1][1] + b1q1[1]));
                au[3] = pk2(silu_(acc1[1][2] + b1q1[2]), silu_(acc1[1][3] + b1q1[3]));
            }

            #pragma unroll
            for (int n = 0; n < 8; ++n) {
                int row = l15 + n * 16;
                bf16x8 w2 = *(const bf16x8*)(Wb + 32768 + row * 256 +
                              ((q * 64 + g * 16) ^ ((row & 7) << 4)));
                acc2[n] = mfma16(w2, a2, acc2[n]);
            }
        }

        // epilogue: lane holds f2 = n*16+g*4+r for edge eb0+l15
        float zed = 0.f;
        #pragma unroll
        for (int n = 0; n < 8; ++n) {
            f32x4 b2q = ((f32x4*)BiasL)[32 + n * 4 + g];
            f32x4 woq = ((f32x4*)BiasL)[64 + n * 4 + g];
            zed += silu_(acc2[n][0] + b2q[0]) * woq[0];
            zed += silu_(acc2[n][1] + b2q[1]) * woq[1];
            zed += silu_(acc2[n][2] + b2q[2]) * woq[2];
            zed += silu_(acc2[n][3] + b2q[3]) * woq[3];
        }
        zed += __shfl_xor(zed, 16, 64);
        zed += __shfl_xor(zed, 32, 64);

        // sigmoid*10, pack bit31 | e<<17 | q17, atomicMax scatter (last-e-wins)
        if (g == 0) {
            int e = eb0 + l15;
            float z = zed + bo0;
            float val = 10.0f * __builtin_amdgcn_rcpf(1.0f + __expf(-z));
            unsigned qv = (unsigned)(val * 13107.0f + 0.5f) + 1u;  // 131070/10
            if (qv > 0x1FFFFu) qv = 0x1FFFFu;
            unsigned packed = 0x80000000u | ((unsigned)e << 17) | qv;
            atomicMax(out + ((size_t)bb * NN_ + (size_t)eis * N_ + eid), packed);
        }
    }
}

// Fused finalize. Cell states: 0 = empty (= final 0.0f); bit31 set = packed
// quantized edge value; bit31 clear & nonzero = already-final float in (0,10].
// Every writer of a cell writes the same v, so concurrent/stale reads are
// benign: a stale read sees the packed form and recomputes the identical v.
__global__ __launch_bounds__(256) void finalize_fused(
    const int* __restrict__ EI, unsigned* __restrict__ out)
{
    int i = blockIdx.x * 256 + threadIdx.x;   // 0..B*E-1
    int b = i >> 14, e = i & 16383;
    int s = EI[(size_t)b * 2 * E_ + e];
    int d = EI[(size_t)b * 2 * E_ + E_ + e];
    unsigned* ob = out + (size_t)b * NN_;
    unsigned x1 = ob[(size_t)s * N_ + d];
    unsigned x2 = ob[(size_t)d * N_ + s];
    float v;
    if (!(x1 >> 31) && x1)      v = __uint_as_float(x1);   // already final
    else if (!(x2 >> 31) && x2) v = __uint_as_float(x2);   // already final
    else {
        float c1 = (x1 >> 31) ? dec17(x1) : 0.0f;
        float c2 = (x2 >> 31) ? dec17(x2) : 0.0f;
        v = 0.5f * (c1 + c2);
    }
    unsigned uv = __float_as_uint(v);
    ob[(size_t)s * N_ + d] = uv;
    ob[(size_t)d * N_ + s] = uv;
}

extern "C" void kernel_launch(void* const* d_in, const int* in_sizes, int n_in,
                              void* d_out, int out_size, void* d_ws, size_t ws_size,
                              hipStream_t stream) {
    const float* X  = (const float*)d_in[0];
    const int*   EI = (const int*)d_in[1];
    const float* W1 = (const float*)d_in[2];
    const float* b1 = (const float*)d_in[3];
    const float* W2 = (const float*)d_in[4];
    const float* b2 = (const float*)d_in[5];
    const float* Wo = (const float*)d_in[6];
    const float* bo = (const float*)d_in[7];
    unsigned* out = (unsigned*)d_out;
    unsigned short* wsz = (unsigned short*)d_ws;

    prep_weights<<<dim3(128), dim3(256), 0, stream>>>(W1, W2, wsz);
    hipMemsetAsync(d_out, 0, (size_t)B_ * NN_ * sizeof(float), stream);
    mlp_scatter_kernel<<<dim3((B_ * E_) / (128 * T_)), dim3(512), 0, stream>>>(
        X, EI, wsz, b1, b2, Wo, bo, out);
    finalize_fused<<<dim3((B_ * E_) / 256), dim3(256), 0, stream>>>(EI, out);
}

// Round 9
// 394.735 us; speedup vs baseline: 1.7634x; 1.7599x over previous
//
#include <hip/hip_runtime.h>
#include <hip/hip_bf16.h>
#include <math.h>

#define B_ 32
#define E_ 16384
#define N_ 1000
#define D_ 128
#define NN_ (N_ * N_)
#define T_ 8   // 128-edge sub-tiles per block; grid = B_*E_/(128*T_) = 512 = 2/CU

typedef __attribute__((ext_vector_type(8))) short bf16x8;
typedef __attribute__((ext_vector_type(4))) float f32x4;

// fp32 -> bf16 RNE (scalar; finite inputs)
__device__ __forceinline__ unsigned short f2bf(float f) {
    unsigned u = __float_as_uint(f);
    u += 0x7FFFu + ((u >> 16) & 1u);
    return (unsigned short)(u >> 16);
}

// packed pair fp32 -> bf16x2 (v_cvt_pk_bf16_f32)
__device__ __forceinline__ unsigned pk2(float lo, float hi) {
    __hip_bfloat162 h = __float22bfloat162_rn(make_float2(lo, hi));
    return *(unsigned*)&h;
}

__device__ __forceinline__ f32x4 mfma16(bf16x8 a, bf16x8 b, f32x4 c) {
    return __builtin_amdgcn_mfma_f32_16x16x32_bf16(a, b, c, 0, 0, 0);
}

__device__ __forceinline__ float silu_(float z) {
    return z * __builtin_amdgcn_rcpf(1.0f + __expf(-z));
}

// decode 17-bit quantized cell payload (call only when bit31 set; q >= 1)
__device__ __forceinline__ float dec17(unsigned x) {
    return (float)((x & 0x1FFFFu) - 1u) * (10.0f / 131070.0f);
}

// async global->LDS, 16B per lane (dest = wave-uniform base + lane*16)
__device__ __forceinline__ void gload_lds16(const void* g, void* l) {
    __builtin_amdgcn_global_load_lds(
        (const __attribute__((address_space(1))) unsigned*)g,
        (__attribute__((address_space(3))) unsigned*)l, 16, 0, 0);
}

// Pre-swizzle W1,W2 (128x128 fp32) -> bf16 at byte row*256 + ((2*pos)^((row&7)<<4)).
// W1: pos = src column (natural).  W2: COLUMN-PERMUTED so GEMM1's C-fragment
// feeds GEMM2 directly with NO transpose: k-slot pos = q*32 + g*8 + nn*4 + r
// holds logical f1 = (q*2+nn)*16 + g*4 + r (where GEMM1's output lands).
__global__ void prep_weights(const float* __restrict__ W1,
                             const float* __restrict__ W2,
                             unsigned short* __restrict__ wsz) {
    int t = blockIdx.x * 256 + threadIdx.x;   // 0..32767
    int w = t >> 14, e = t & 16383;
    int row = e >> 7, pos = e & 127;
    int src_col = pos;
    if (w) {
        int q = pos >> 5, gg = (pos >> 3) & 3, nn = (pos >> 2) & 1, r = pos & 3;
        src_col = (q * 2 + nn) * 16 + gg * 4 + r;
    }
    float v = (w ? W2 : W1)[row * 128 + src_col];
    char* dst = (char*)wsz + (size_t)w * 32768 + row * 256 + ((pos * 2) ^ ((row & 7) << 4));
    *(unsigned short*)dst = f2bf(v);
}

// launch_bounds(512, 2): empirically the 2nd arg acted as min-BLOCKS/CU in
// rounds 7/8 ((512,4) -> 64-VGPR cap -> massive scratch spill, FETCH 1.3GB).
// (512,2) = 16 waves/CU = 4 waves/SIMD -> 128-VGPR cap, fits the ~100-reg body.
__global__ __launch_bounds__(512, 2) void mlp_scatter_kernel(
    const float* __restrict__ X, const int* __restrict__ EI,
    const unsigned short* __restrict__ wsz,
    const float* __restrict__ b1, const float* __restrict__ b2,
    const float* __restrict__ Wo, const float* __restrict__ bo,
    unsigned* __restrict__ out)
{
    __shared__ __align__(16) char Wb[65536];   // W1 | W2 bf16, swizzled
    __shared__ __align__(16) float BiasL[384]; // b1 | b2 | Wo (fp32)

    const int tid = threadIdx.x;
    const int lane = tid & 63;
    const int wv = tid >> 6;          // wave 0..7, owns 16 edges per sub-tile
    const int l15 = lane & 15;
    const int g = (lane >> 4) & 3;

    const int bb = blockIdx.x >> 4;                 // batch (16 blocks per batch)
    const int e0 = (blockIdx.x & 15) * (128 * T_);  // 1024 edges per block

    if (tid < 96) {
        const float* src = tid < 32 ? b1 : (tid < 64 ? b2 : Wo);
        ((f32x4*)BiasL)[tid] = ((const f32x4*)src)[tid & 31];
    }
    const float bo0 = bo[0];

    // stage both weight matrices: 64KB linear, zero VALU
    #pragma unroll
    for (int it = 0; it < 8; ++it) {
        int off = it * 8192 + tid * 16;
        gload_lds16((const char*)wsz + off, Wb + off);
    }
    __syncthreads();

    for (int st = 0; st < T_; ++st) {   // NOT unrolled: limits register liveness
        const int eb0 = e0 + st * 128 + wv * 16;

        const int eis = EI[(size_t)bb * 2 * E_ + eb0 + l15];
        const int eid = EI[(size_t)bb * 2 * E_ + E_ + eb0 + l15];

        // load X for this wave's 16 edges; convert incrementally (low liveness)
        bf16x8 a[4];
        {
            const float* p0 = X + ((size_t)bb * E_ + eb0 + l15) * D_ + g * 8;
            #pragma unroll
            for (int ks = 0; ks < 4; ++ks) {
                float4 u0 = *(const float4*)(p0 + ks * 32);
                float4 u1 = *(const float4*)(p0 + ks * 32 + 4);
                bf16x8 t; unsigned* tu = (unsigned*)&t;
                tu[0] = pk2(u0.x, u0.y); tu[1] = pk2(u0.z, u0.w);
                tu[2] = pk2(u1.x, u1.y); tu[3] = pk2(u1.z, u1.w);
                a[ks] = t;
            }
        }

        f32x4 acc2[8];
        #pragma unroll
        for (int n = 0; n < 8; ++n)
            acc2[n] = (f32x4){0.f, 0.f, 0.f, 0.f};

        // quarter-feature pipeline: GEMM1 q -> (bias+silu+pack in REGS) -> GEMM2 q
        #pragma unroll
        for (int q = 0; q < 4; ++q) {
            f32x4 acc1[2];
            acc1[0] = (f32x4){0.f, 0.f, 0.f, 0.f};
            acc1[1] = (f32x4){0.f, 0.f, 0.f, 0.f};

            #pragma unroll
            for (int ks = 0; ks < 4; ++ks)
                #pragma unroll
                for (int nn = 0; nn < 2; ++nn) {
                    int row = l15 + (q * 2 + nn) * 16;
                    bf16x8 aw = *(const bf16x8*)(Wb + row * 256 +
                                  ((ks * 64 + g * 16) ^ ((row & 7) << 4)));
                    acc1[nn] = mfma16(aw, a[ks], acc1[nn]);
                }

            // h fragment in-register: k-slot (g, nn*4+r) = acc1[nn][r]
            // (W2 columns pre-permuted to match)
            bf16x8 a2;
            {
                f32x4 b1q0 = ((f32x4*)BiasL)[(q * 2 + 0) * 4 + g];
                f32x4 b1q1 = ((f32x4*)BiasL)[(q * 2 + 1) * 4 + g];
                unsigned* au = (unsigned*)&a2;
                au[0] = pk2(silu_(acc1[0][0] + b1q0[0]), silu_(acc1[0][1] + b1q0[1]));
                au[1] = pk2(silu_(acc1[0][2] + b1q0[2]), silu_(acc1[0][3] + b1q0[3]));
                au[2] = pk2(silu_(acc1[1][0] + b1q1[0]), silu_(acc1[1][1] + b1q1[1]));
                au[3] = pk2(silu_(acc1[1][2] + b1q1[2]), silu_(acc1[1][3] + b1q1[3]));
            }

            #pragma unroll
            for (int n = 0; n < 8; ++n) {
                int row = l15 + n * 16;
                bf16x8 w2 = *(const bf16x8*)(Wb + 32768 + row * 256 +
                              ((q * 64 + g * 16) ^ ((row & 7) << 4)));
                acc2[n] = mfma16(w2, a2, acc2[n]);
            }
        }

        // epilogue: lane holds f2 = n*16+g*4+r for edge eb0+l15
        float zed = 0.f;
        #pragma unroll
        for (int n = 0; n < 8; ++n) {
            f32x4 b2q = ((f32x4*)BiasL)[32 + n * 4 + g];
            f32x4 woq = ((f32x4*)BiasL)[64 + n * 4 + g];
            zed += silu_(acc2[n][0] + b2q[0]) * woq[0];
            zed += silu_(acc2[n][1] + b2q[1]) * woq[1];
            zed += silu_(acc2[n][2] + b2q[2]) * woq[2];
            zed += silu_(acc2[n][3] + b2q[3]) * woq[3];
        }
        zed += __shfl_xor(zed, 16, 64);
        zed += __shfl_xor(zed, 32, 64);

        // sigmoid*10, pack bit31 | e<<17 | q17, atomicMax scatter (last-e-wins)
        if (g == 0) {
            int e = eb0 + l15;
            float z = zed + bo0;
            float val = 10.0f * __builtin_amdgcn_rcpf(1.0f + __expf(-z));
            unsigned qv = (unsigned)(val * 13107.0f + 0.5f) + 1u;  // 131070/10
            if (qv > 0x1FFFFu) qv = 0x1FFFFu;
            unsigned packed = 0x80000000u | ((unsigned)e << 17) | qv;
            atomicMax(out + ((size_t)bb * NN_ + (size_t)eis * N_ + eid), packed);
        }
    }
}

// Fused finalize. Cell states: 0 = empty (= final 0.0f); bit31 set = packed
// quantized edge value; bit31 clear & nonzero = already-final float in (0,10].
// Every writer of a cell writes the same v, so concurrent/stale reads are
// benign: a stale read sees the packed form and recomputes the identical v.
__global__ __launch_bounds__(256) void finalize_fused(
    const int* __restrict__ EI, unsigned* __restrict__ out)
{
    int i = blockIdx.x * 256 + threadIdx.x;   // 0..B*E-1
    int b = i >> 14, e = i & 16383;
    int s = EI[(size_t)b * 2 * E_ + e];
    int d = EI[(size_t)b * 2 * E_ + E_ + e];
    unsigned* ob = out + (size_t)b * NN_;
    unsigned x1 = ob[(size_t)s * N_ + d];
    unsigned x2 = ob[(size_t)d * N_ + s];
    float v;
    if (!(x1 >> 31) && x1)      v = __uint_as_float(x1);   // already final
    else if (!(x2 >> 31) && x2) v = __uint_as_float(x2);   // already final
    else {
        float c1 = (x1 >> 31) ? dec17(x1) : 0.0f;
        float c2 = (x2 >> 31) ? dec17(x2) : 0.0f;
        v = 0.5f * (c1 + c2);
    }
    unsigned uv = __float_as_uint(v);
    ob[(size_t)s * N_ + d] = uv;
    ob[(size_t)d * N_ + s] = uv;
}

extern "C" void kernel_launch(void* const* d_in, const int* in_sizes, int n_in,
                              void* d_out, int out_size, void* d_ws, size_t ws_size,
                              hipStream_t stream) {
    const float* X  = (const float*)d_in[0];
    const int*   EI = (const int*)d_in[1];
    const float* W1 = (const float*)d_in[2];
    const float* b1 = (const float*)d_in[3];
    const float* W2 = (const float*)d_in[4];
    const float* b2 = (const float*)d_in[5];
    const float* Wo = (const float*)d_in[6];
    const float* bo = (const float*)d_in[7];
    unsigned* out = (unsigned*)d_out;
    unsigned short* wsz = (unsigned short*)d_ws;

    prep_weights<<<dim3(128), dim3(256), 0, stream>>>(W1, W2, wsz);
    hipMemsetAsync(d_out, 0, (size_t)B_ * NN_ * sizeof(float), stream);
    mlp_scatter_kernel<<<dim3((B_ * E_) / (128 * T_)), dim3(512), 0, stream>>>(
        X, EI, wsz, b1, b2, Wo, bo, out);
    finalize_fused<<<dim3((B_ * E_) / 256), dim3(256), 0, stream>>>(EI, out);
}

// Round 10
// 143.892 us; speedup vs baseline: 4.8374x; 2.7433x over previous
//
#include <hip/hip_runtime.h>
#include <hip/hip_bf16.h>
#include <math.h>

#define B_ 32
#define E_ 16384
#define N_ 1000
#define D_ 128
#define NN_ (N_ * N_)
#define T_ 8   // 128-edge sub-tiles per block (8 waves x 16 edges); grid = 512 = 2/CU

typedef __attribute__((ext_vector_type(8))) short bf16x8;
typedef __attribute__((ext_vector_type(4))) float f32x4;

// fp32 -> bf16 RNE (scalar; finite inputs)
__device__ __forceinline__ unsigned short f2bf(float f) {
    unsigned u = __float_as_uint(f);
    u += 0x7FFFu + ((u >> 16) & 1u);
    return (unsigned short)(u >> 16);
}

// packed pair fp32 -> bf16x2 (v_cvt_pk_bf16_f32)
__device__ __forceinline__ unsigned pk2(float lo, float hi) {
    __hip_bfloat162 h = __float22bfloat162_rn(make_float2(lo, hi));
    return *(unsigned*)&h;
}

__device__ __forceinline__ f32x4 mfma16(bf16x8 a, bf16x8 b, f32x4 c) {
    return __builtin_amdgcn_mfma_f32_16x16x32_bf16(a, b, c, 0, 0, 0);
}

__device__ __forceinline__ float silu_(float z) {
    return z * __builtin_amdgcn_rcpf(1.0f + __expf(-z));
}

// decode 17-bit quantized cell payload (call only when bit31 set; q >= 1)
__device__ __forceinline__ float dec17(unsigned x) {
    return (float)((x & 0x1FFFFu) - 1u) * (10.0f / 131070.0f);
}

// async global->LDS, 16B per lane (dest = wave-uniform base + lane*16)
__device__ __forceinline__ void gload_lds16(const void* g, void* l) {
    __builtin_amdgcn_global_load_lds(
        (const __attribute__((address_space(1))) unsigned*)g,
        (__attribute__((address_space(3))) unsigned*)l, 16, 0, 0);
}

// Pre-swizzle W1,W2 (128x128 fp32) -> bf16 at byte row*256 + ((2*pos)^((row&7)<<4)).
// W1: pos = src column (natural).  W2: COLUMN-PERMUTED so GEMM1's C-fragment
// feeds GEMM2 directly with NO transpose: k-slot pos = q*32 + g*8 + nn*4 + r
// holds logical f1 = (q*2+nn)*16 + g*4 + r (where GEMM1's output lands).
__global__ void prep_weights(const float* __restrict__ W1,
                             const float* __restrict__ W2,
                             unsigned short* __restrict__ wsz) {
    int t = blockIdx.x * 256 + threadIdx.x;   // 0..32767
    int w = t >> 14, e = t & 16383;
    int row = e >> 7, pos = e & 127;
    int src_col = pos;
    if (w) {
        int q = pos >> 5, gg = (pos >> 3) & 3, nn = (pos >> 2) & 1, r = pos & 3;
        src_col = (q * 2 + nn) * 16 + gg * 4 + r;
    }
    float v = (w ? W2 : W1)[row * 128 + src_col];
    char* dst = (char*)wsz + (size_t)w * 32768 + row * 256 + ((pos * 2) ^ ((row & 7) << 4));
    *(unsigned short*)dst = f2bf(v);
}

// (512,2): 2 blocks/CU (LDS-limited anyway) = 16 waves/CU, 128-VGPR cap.
// Body is PHASE-SEPARATED so peak liveness fits 128 (see per-phase comments).
__global__ __launch_bounds__(512, 2) void mlp_scatter_kernel(
    const float* __restrict__ X, const int* __restrict__ EI,
    const unsigned short* __restrict__ wsz,
    const float* __restrict__ b1, const float* __restrict__ b2,
    const float* __restrict__ Wo, const float* __restrict__ bo,
    unsigned* __restrict__ out)
{
    __shared__ __align__(16) char Wb[65536];   // W1 | W2 bf16, swizzled
    __shared__ __align__(16) float BiasL[384]; // b1 | b2 | Wo (fp32)

    const int tid = threadIdx.x;
    const int lane = tid & 63;
    const int wv = tid >> 6;          // wave 0..7, owns 16 edges per sub-tile
    const int l15 = lane & 15;
    const int g = (lane >> 4) & 3;

    const int bb = blockIdx.x >> 4;                 // batch (16 blocks per batch)
    const int e0 = (blockIdx.x & 15) * (128 * T_);  // 1024 edges per block

    if (tid < 96) {
        const float* src = tid < 32 ? b1 : (tid < 64 ? b2 : Wo);
        ((f32x4*)BiasL)[tid] = ((const f32x4*)src)[tid & 31];
    }
    const float bo0 = bo[0];

    // stage both weight matrices: 64KB linear, zero VALU
    #pragma unroll
    for (int it = 0; it < 8; ++it) {
        int off = it * 8192 + tid * 16;
        gload_lds16((const char*)wsz + off, Wb + off);
    }
    __syncthreads();

    #pragma unroll 1   // runtime loop: keeps per-iteration liveness bounded
    for (int st = 0; st < T_; ++st) {
        const int eb0 = e0 + st * 128 + wv * 16;

        const int eis = EI[(size_t)bb * 2 * E_ + eb0 + l15];
        const int eid = EI[(size_t)bb * 2 * E_ + E_ + eb0 + l15];

        // ---- load X for this wave's 16 edges (16 regs live) ----
        bf16x8 a[4];
        {
            const float* p0 = X + ((size_t)bb * E_ + eb0 + l15) * D_ + g * 8;
            #pragma unroll
            for (int ks = 0; ks < 4; ++ks) {
                float4 u0 = *(const float4*)(p0 + ks * 32);
                float4 u1 = *(const float4*)(p0 + ks * 32 + 4);
                bf16x8 t; unsigned* tu = (unsigned*)&t;
                tu[0] = pk2(u0.x, u0.y); tu[1] = pk2(u0.z, u0.w);
                tu[2] = pk2(u1.x, u1.y); tu[3] = pk2(u1.z, u1.w);
                a[ks] = t;
            }
        }

        // ---- PHASE 1: all GEMM1 quarters -> pa[4] (a dies at phase end) ----
        // peak: a(16) + pa(<=16) + acc1(8) + aw transients(<=32) ~ 75 regs
        bf16x8 pa[4];
        #pragma unroll
        for (int q = 0; q < 4; ++q) {
            f32x4 acc1[2];
            acc1[0] = (f32x4){0.f, 0.f, 0.f, 0.f};
            acc1[1] = (f32x4){0.f, 0.f, 0.f, 0.f};

            #pragma unroll
            for (int ks = 0; ks < 4; ++ks)
                #pragma unroll
                for (int nn = 0; nn < 2; ++nn) {
                    int row = l15 + (q * 2 + nn) * 16;
                    bf16x8 aw = *(const bf16x8*)(Wb + row * 256 +
                                  ((ks * 64 + g * 16) ^ ((row & 7) << 4)));
                    acc1[nn] = mfma16(aw, a[ks], acc1[nn]);
                }

            // h fragment in-register: k-slot (g, nn*4+r) = acc1[nn][r]
            f32x4 b1q0 = ((f32x4*)BiasL)[(q * 2 + 0) * 4 + g];
            f32x4 b1q1 = ((f32x4*)BiasL)[(q * 2 + 1) * 4 + g];
            unsigned* au = (unsigned*)&pa[q];
            au[0] = pk2(silu_(acc1[0][0] + b1q0[0]), silu_(acc1[0][1] + b1q0[1]));
            au[1] = pk2(silu_(acc1[0][2] + b1q0[2]), silu_(acc1[0][3] + b1q0[3]));
            au[2] = pk2(silu_(acc1[1][0] + b1q1[0]), silu_(acc1[1][1] + b1q1[1]));
            au[3] = pk2(silu_(acc1[1][2] + b1q1[2]), silu_(acc1[1][3] + b1q1[3]));
            __builtin_amdgcn_sched_barrier(0);   // no cross-q hoisting
        }

        // ---- PHASE 2: GEMM2, q-major; acc2 born after a died ----
        // peak: acc2(32) + pa(16) + w2 transients(<=32) + misc ~ 100 regs
        f32x4 acc2[8];
        #pragma unroll
        for (int n = 0; n < 8; ++n)
            acc2[n] = (f32x4){0.f, 0.f, 0.f, 0.f};

        #pragma unroll
        for (int q = 0; q < 4; ++q) {
            #pragma unroll
            for (int n = 0; n < 8; ++n) {
                int row = l15 + n * 16;
                bf16x8 w2 = *(const bf16x8*)(Wb + 32768 + row * 256 +
                              ((q * 64 + g * 16) ^ ((row & 7) << 4)));
                acc2[n] = mfma16(w2, pa[q], acc2[n]);
            }
            __builtin_amdgcn_sched_barrier(0);   // cap ds-read transients per q
        }

        // ---- epilogue: lane holds f2 = n*16+g*4+r for edge eb0+l15 ----
        float zed = 0.f;
        #pragma unroll
        for (int n = 0; n < 8; ++n) {
            f32x4 b2q = ((f32x4*)BiasL)[32 + n * 4 + g];
            f32x4 woq = ((f32x4*)BiasL)[64 + n * 4 + g];
            zed += silu_(acc2[n][0] + b2q[0]) * woq[0];
            zed += silu_(acc2[n][1] + b2q[1]) * woq[1];
            zed += silu_(acc2[n][2] + b2q[2]) * woq[2];
            zed += silu_(acc2[n][3] + b2q[3]) * woq[3];
        }
        zed += __shfl_xor(zed, 16, 64);
        zed += __shfl_xor(zed, 32, 64);

        // sigmoid*10, pack bit31 | e<<17 | q17, atomicMax scatter (last-e-wins)
        if (g == 0) {
            int e = eb0 + l15;
            float z = zed + bo0;
            float val = 10.0f * __builtin_amdgcn_rcpf(1.0f + __expf(-z));
            unsigned qv = (unsigned)(val * 13107.0f + 0.5f) + 1u;  // 131070/10
            if (qv > 0x1FFFFu) qv = 0x1FFFFu;
            unsigned packed = 0x80000000u | ((unsigned)e << 17) | qv;
            atomicMax(out + ((size_t)bb * NN_ + (size_t)eis * N_ + eid), packed);
        }
    }
}

// Fused finalize. Cell states: 0 = empty (= final 0.0f); bit31 set = packed
// quantized edge value; bit31 clear & nonzero = already-final float in (0,10].
// Every writer of a cell writes the same v, so concurrent/stale reads are
// benign: a stale read sees the packed form and recomputes the identical v.
__global__ __launch_bounds__(256) void finalize_fused(
    const int* __restrict__ EI, unsigned* __restrict__ out)
{
    int i = blockIdx.x * 256 + threadIdx.x;   // 0..B*E-1
    int b = i >> 14, e = i & 16383;
    int s = EI[(size_t)b * 2 * E_ + e];
    int d = EI[(size_t)b * 2 * E_ + E_ + e];
    unsigned* ob = out + (size_t)b * NN_;
    unsigned x1 = ob[(size_t)s * N_ + d];
    unsigned x2 = ob[(size_t)d * N_ + s];
    float v;
    if (!(x1 >> 31) && x1)      v = __uint_as_float(x1);   // already final
    else if (!(x2 >> 31) && x2) v = __uint_as_float(x2);   // already final
    else {
        float c1 = (x1 >> 31) ? dec17(x1) : 0.0f;
        float c2 = (x2 >> 31) ? dec17(x2) : 0.0f;
        v = 0.5f * (c1 + c2);
    }
    unsigned uv = __float_as_uint(v);
    ob[(size_t)s * N_ + d] = uv;
    ob[(size_t)d * N_ + s] = uv;
}

extern "C" void kernel_launch(void* const* d_in, const int* in_sizes, int n_in,
                              void* d_out, int out_size, void* d_ws, size_t ws_size,
                              hipStream_t stream) {
    const float* X  = (const float*)d_in[0];
    const int*   EI = (const int*)d_in[1];
    const float* W1 = (const float*)d_in[2];
    const float* b1 = (const float*)d_in[3];
    const float* W2 = (const float*)d_in[4];
    const float* b2 = (const float*)d_in[5];
    const float* Wo = (const float*)d_in[6];
    const float* bo = (const float*)d_in[7];
    unsigned* out = (unsigned*)d_out;
    unsigned short* wsz = (unsigned short*)d_ws;

    prep_weights<<<dim3(128), dim3(256), 0, stream>>>(W1, W2, wsz);
    hipMemsetAsync(d_out, 0, (size_t)B_ * NN_ * sizeof(float), stream);
    mlp_scatter_kernel<<<dim3((B_ * E_) / (128 * T_)), dim3(512), 0, stream>>>(
        X, EI, wsz, b1, b2, Wo, bo, out);
    finalize_fused<<<dim3((B_ * E_) / 256), dim3(256), 0, stream>>>(EI, out);
}

// Round 11
// 142.576 us; speedup vs baseline: 4.8820x; 1.0092x over previous
//
#include <hip/hip_runtime.h>
#include <hip/hip_bf16.h>
#include <math.h>

#define B_ 32
#define E_ 16384
#define N_ 1000
#define D_ 128
#define NN_ (N_ * N_)
#define T_ 8   // 128-edge sub-tiles per block (8 waves x 16 edges); grid = 512 = 2/CU

typedef __attribute__((ext_vector_type(8))) short bf16x8;
typedef __attribute__((ext_vector_type(4))) float f32x4;

// fp32 -> bf16 RNE (scalar; finite inputs)
__device__ __forceinline__ unsigned short f2bf(float f) {
    unsigned u = __float_as_uint(f);
    u += 0x7FFFu + ((u >> 16) & 1u);
    return (unsigned short)(u >> 16);
}

// packed pair fp32 -> bf16x2 (v_cvt_pk_bf16_f32)
__device__ __forceinline__ unsigned pk2(float lo, float hi) {
    __hip_bfloat162 h = __float22bfloat162_rn(make_float2(lo, hi));
    return *(unsigned*)&h;
}

__device__ __forceinline__ f32x4 mfma16(bf16x8 a, bf16x8 b, f32x4 c) {
    return __builtin_amdgcn_mfma_f32_16x16x32_bf16(a, b, c, 0, 0, 0);
}

__device__ __forceinline__ float silu_(float z) {
    return z * __builtin_amdgcn_rcpf(1.0f + __expf(-z));
}

// decode 17-bit quantized cell payload (call only when bit31 set; q >= 1)
__device__ __forceinline__ float dec17(unsigned x) {
    return (float)((x & 0x1FFFFu) - 1u) * (10.0f / 131070.0f);
}

// async global->LDS, 16B per lane (dest = wave-uniform base + lane*16)
__device__ __forceinline__ void gload_lds16(const void* g, void* l) {
    __builtin_amdgcn_global_load_lds(
        (const __attribute__((address_space(1))) unsigned*)g,
        (__attribute__((address_space(3))) unsigned*)l, 16, 0, 0);
}

// Custom zero-fill: the rocclr fillBufferAligned kernel ran at ~0.84 TB/s
// (10.8% occupancy, small grid) and dominated the total (~140us floor across
// rounds 5/6/10). Grid-stride uint4 stores at 2048x256 hit write-BW ceiling.
__global__ __launch_bounds__(256) void fill_zero(uint4* __restrict__ p, int n4) {
    int i = blockIdx.x * 256 + threadIdx.x;
    const int stride = gridDim.x * 256;
    const uint4 z = make_uint4(0u, 0u, 0u, 0u);
    for (; i < n4; i += stride) p[i] = z;
}

// Pre-swizzle W1,W2 (128x128 fp32) -> bf16 at byte row*256 + ((2*pos)^((row&7)<<4)).
// W1: pos = src column (natural).  W2: COLUMN-PERMUTED so GEMM1's C-fragment
// feeds GEMM2 directly with NO transpose: k-slot pos = q*32 + g*8 + nn*4 + r
// holds logical f1 = (q*2+nn)*16 + g*4 + r (where GEMM1's output lands).
__global__ void prep_weights(const float* __restrict__ W1,
                             const float* __restrict__ W2,
                             unsigned short* __restrict__ wsz) {
    int t = blockIdx.x * 256 + threadIdx.x;   // 0..32767
    int w = t >> 14, e = t & 16383;
    int row = e >> 7, pos = e & 127;
    int src_col = pos;
    if (w) {
        int q = pos >> 5, gg = (pos >> 3) & 3, nn = (pos >> 2) & 1, r = pos & 3;
        src_col = (q * 2 + nn) * 16 + gg * 4 + r;
    }
    float v = (w ? W2 : W1)[row * 128 + src_col];
    char* dst = (char*)wsz + (size_t)w * 32768 + row * 256 + ((pos * 2) ^ ((row & 7) << 4));
    *(unsigned short*)dst = f2bf(v);
}

// (512,2): 2 blocks/CU (LDS-limited anyway) = 16 waves/CU, 128-VGPR cap.
// Body is PHASE-SEPARATED so peak liveness fits 128 (see per-phase comments).
__global__ __launch_bounds__(512, 2) void mlp_scatter_kernel(
    const float* __restrict__ X, const int* __restrict__ EI,
    const unsigned short* __restrict__ wsz,
    const float* __restrict__ b1, const float* __restrict__ b2,
    const float* __restrict__ Wo, const float* __restrict__ bo,
    unsigned* __restrict__ out)
{
    __shared__ __align__(16) char Wb[65536];   // W1 | W2 bf16, swizzled
    __shared__ __align__(16) float BiasL[384]; // b1 | b2 | Wo (fp32)

    const int tid = threadIdx.x;
    const int lane = tid & 63;
    const int wv = tid >> 6;          // wave 0..7, owns 16 edges per sub-tile
    const int l15 = lane & 15;
    const int g = (lane >> 4) & 3;

    const int bb = blockIdx.x >> 4;                 // batch (16 blocks per batch)
    const int e0 = (blockIdx.x & 15) * (128 * T_);  // 1024 edges per block

    if (tid < 96) {
        const float* src = tid < 32 ? b1 : (tid < 64 ? b2 : Wo);
        ((f32x4*)BiasL)[tid] = ((const f32x4*)src)[tid & 31];
    }
    const float bo0 = bo[0];

    // stage both weight matrices: 64KB linear, zero VALU
    #pragma unroll
    for (int it = 0; it < 8; ++it) {
        int off = it * 8192 + tid * 16;
        gload_lds16((const char*)wsz + off, Wb + off);
    }
    __syncthreads();

    #pragma unroll 1   // runtime loop: keeps per-iteration liveness bounded
    for (int st = 0; st < T_; ++st) {
        const int eb0 = e0 + st * 128 + wv * 16;

        const int eis = EI[(size_t)bb * 2 * E_ + eb0 + l15];
        const int eid = EI[(size_t)bb * 2 * E_ + E_ + eb0 + l15];

        // ---- load X for this wave's 16 edges (16 regs live) ----
        bf16x8 a[4];
        {
            const float* p0 = X + ((size_t)bb * E_ + eb0 + l15) * D_ + g * 8;
            #pragma unroll
            for (int ks = 0; ks < 4; ++ks) {
                float4 u0 = *(const float4*)(p0 + ks * 32);
                float4 u1 = *(const float4*)(p0 + ks * 32 + 4);
                bf16x8 t; unsigned* tu = (unsigned*)&t;
                tu[0] = pk2(u0.x, u0.y); tu[1] = pk2(u0.z, u0.w);
                tu[2] = pk2(u1.x, u1.y); tu[3] = pk2(u1.z, u1.w);
                a[ks] = t;
            }
        }

        // ---- PHASE 1: all GEMM1 quarters -> pa[4] (a dies at phase end) ----
        // peak: a(16) + pa(<=16) + acc1(8) + aw transients(<=32) ~ 75 regs
        bf16x8 pa[4];
        #pragma unroll
        for (int q = 0; q < 4; ++q) {
            f32x4 acc1[2];
            acc1[0] = (f32x4){0.f, 0.f, 0.f, 0.f};
            acc1[1] = (f32x4){0.f, 0.f, 0.f, 0.f};

            #pragma unroll
            for (int ks = 0; ks < 4; ++ks)
                #pragma unroll
                for (int nn = 0; nn < 2; ++nn) {
                    int row = l15 + (q * 2 + nn) * 16;
                    bf16x8 aw = *(const bf16x8*)(Wb + row * 256 +
                                  ((ks * 64 + g * 16) ^ ((row & 7) << 4)));
                    acc1[nn] = mfma16(aw, a[ks], acc1[nn]);
                }

            // h fragment in-register: k-slot (g, nn*4+r) = acc1[nn][r]
            f32x4 b1q0 = ((f32x4*)BiasL)[(q * 2 + 0) * 4 + g];
            f32x4 b1q1 = ((f32x4*)BiasL)[(q * 2 + 1) * 4 + g];
            unsigned* au = (unsigned*)&pa[q];
            au[0] = pk2(silu_(acc1[0][0] + b1q0[0]), silu_(acc1[0][1] + b1q0[1]));
            au[1] = pk2(silu_(acc1[0][2] + b1q0[2]), silu_(acc1[0][3] + b1q0[3]));
            au[2] = pk2(silu_(acc1[1][0] + b1q1[0]), silu_(acc1[1][1] + b1q1[1]));
            au[3] = pk2(silu_(acc1[1][2] + b1q1[2]), silu_(acc1[1][3] + b1q1[3]));
            __builtin_amdgcn_sched_barrier(0);   // no cross-q hoisting
        }

        // ---- PHASE 2: GEMM2, q-major; acc2 born after a died ----
        // peak: acc2(32) + pa(16) + w2 transients(<=32) + misc ~ 100 regs
        f32x4 acc2[8];
        #pragma unroll
        for (int n = 0; n < 8; ++n)
            acc2[n] = (f32x4){0.f, 0.f, 0.f, 0.f};

        #pragma unroll
        for (int q = 0; q < 4; ++q) {
            #pragma unroll
            for (int n = 0; n < 8; ++n) {
                int row = l15 + n * 16;
                bf16x8 w2 = *(const bf16x8*)(Wb + 32768 + row * 256 +
                              ((q * 64 + g * 16) ^ ((row & 7) << 4)));
                acc2[n] = mfma16(w2, pa[q], acc2[n]);
            }
            __builtin_amdgcn_sched_barrier(0);   // cap ds-read transients per q
        }

        // ---- epilogue: lane holds f2 = n*16+g*4+r for edge eb0+l15 ----
        float zed = 0.f;
        #pragma unroll
        for (int n = 0; n < 8; ++n) {
            f32x4 b2q = ((f32x4*)BiasL)[32 + n * 4 + g];
            f32x4 woq = ((f32x4*)BiasL)[64 + n * 4 + g];
            zed += silu_(acc2[n][0] + b2q[0]) * woq[0];
            zed += silu_(acc2[n][1] + b2q[1]) * woq[1];
            zed += silu_(acc2[n][2] + b2q[2]) * woq[2];
            zed += silu_(acc2[n][3] + b2q[3]) * woq[3];
        }
        zed += __shfl_xor(zed, 16, 64);
        zed += __shfl_xor(zed, 32, 64);

        // sigmoid*10, pack bit31 | e<<17 | q17, atomicMax scatter (last-e-wins)
        if (g == 0) {
            int e = eb0 + l15;
            float z = zed + bo0;
            float val = 10.0f * __builtin_amdgcn_rcpf(1.0f + __expf(-z));
            unsigned qv = (unsigned)(val * 13107.0f + 0.5f) + 1u;  // 131070/10
            if (qv > 0x1FFFFu) qv = 0x1FFFFu;
            unsigned packed = 0x80000000u | ((unsigned)e << 17) | qv;
            atomicMax(out + ((size_t)bb * NN_ + (size_t)eis * N_ + eid), packed);
        }
    }
}

// Fused finalize. Cell states: 0 = empty (= final 0.0f); bit31 set = packed
// quantized edge value; bit31 clear & nonzero = already-final float in (0,10].
// Every writer of a cell writes the same v, so concurrent/stale reads are
// benign: a stale read sees the packed form and recomputes the identical v.
__global__ __launch_bounds__(256) void finalize_fused(
    const int* __restrict__ EI, unsigned* __restrict__ out)
{
    int i = blockIdx.x * 256 + threadIdx.x;   // 0..B*E-1
    int b = i >> 14, e = i & 16383;
    int s = EI[(size_t)b * 2 * E_ + e];
    int d = EI[(size_t)b * 2 * E_ + E_ + e];
    unsigned* ob = out + (size_t)b * NN_;
    unsigned x1 = ob[(size_t)s * N_ + d];
    unsigned x2 = ob[(size_t)d * N_ + s];
    float v;
    if (!(x1 >> 31) && x1)      v = __uint_as_float(x1);   // already final
    else if (!(x2 >> 31) && x2) v = __uint_as_float(x2);   // already final
    else {
        float c1 = (x1 >> 31) ? dec17(x1) : 0.0f;
        float c2 = (x2 >> 31) ? dec17(x2) : 0.0f;
        v = 0.5f * (c1 + c2);
    }
    unsigned uv = __float_as_uint(v);
    ob[(size_t)s * N_ + d] = uv;
    ob[(size_t)d * N_ + s] = uv;
}

extern "C" void kernel_launch(void* const* d_in, const int* in_sizes, int n_in,
                              void* d_out, int out_size, void* d_ws, size_t ws_size,
                              hipStream_t stream) {
    const float* X  = (const float*)d_in[0];
    const int*   EI = (const int*)d_in[1];
    const float* W1 = (const float*)d_in[2];
    const float* b1 = (const float*)d_in[3];
    const float* W2 = (const float*)d_in[4];
    const float* b2 = (const float*)d_in[5];
    const float* Wo = (const float*)d_in[6];
    const float* bo = (const float*)d_in[7];
    unsigned* out = (unsigned*)d_out;
    unsigned short* wsz = (unsigned short*)d_ws;

    // out_size = 32e6 floats = 128e6 bytes, divisible by 16
    fill_zero<<<dim3(2048), dim3(256), 0, stream>>>((uint4*)d_out, out_size / 4);
    prep_weights<<<dim3(128), dim3(256), 0, stream>>>(W1, W2, wsz);
    mlp_scatter_kernel<<<dim3((B_ * E_) / (128 * T_)), dim3(512), 0, stream>>>(
        X, EI, wsz, b1, b2, Wo, bo, out);
    finalize_fused<<<dim3((B_ * E_) / 256), dim3(256), 0, stream>>>(EI, out);
}